// Round 2
// baseline (487.375 us; speedup 1.0000x reference)
//
#include <hip/hip_runtime.h>

// 2-layer tanh RNN, T=2048, B=4096, I=3, H=5. f32 storage.
//
// R7: R6 measured 355 cy/step vs ~70 cy issue -> the two ds_swizzle
// broadcasts (LDS pipe, ~120 cy latency each) dominate the recurrence
// critical path. This version uses 4 lanes/chain and replaces ds_swizzle
// with DPP quad_perm (pure VALU, ~4-8 cy):
//   - lane l owns unit l (slot A) of both layers
//   - EVERY lane redundantly computes unit 4 (slot B) -> unit 4 needs no
//     broadcast; units 0-3 broadcast via 4 independent quad_perm movs
//   - slots A/B packed as float2 -> v_pk_fma_f32 halves dot issue count
// Per-unit accumulation order and tanh formula are bit-identical to R6
// (pk_fma is two independent IEEE fmas), so absmax is unchanged.

typedef float v2f __attribute__((ext_vector_type(2)));

#define SEQ_T 2048
#define BATCH 4096
#define ISZ 3
#define HSZ 5
#define KB 16                   // x prefetch modulo-buffer depth (steps)
#define NBLK (SEQ_T / KB)

// broadcast lane (quad_base + K)'s value to all 4 lanes of the quad.
// quad_perm ctrl = K repeated in all four 2-bit fields = K * 0x55.
template<int K>
__device__ __forceinline__ float qbcast(float v) {
    return __int_as_float(__builtin_amdgcn_mov_dpp(
        __float_as_int(v), K * 0x55, 0xF, 0xF, false));
}

// input pre-scaled by S = 2*log2(e): tanh(z) = 1 - 2*rcp(1 + exp2(S*z))
__device__ __forceinline__ float tanh_fast(float a) {
    float e = __builtin_amdgcn_exp2f(a);
    return fmaf(-2.0f, __builtin_amdgcn_rcpf(1.0f + e), 1.0f);
}

__device__ __forceinline__ v2f vsplat(float s) { return (v2f){s, s}; }
__device__ __forceinline__ v2f vfma(float s, v2f w, v2f a) {
    return __builtin_elementwise_fma(vsplat(s), w, a);  // v_pk_fma_f32
}

__global__ __launch_bounds__(64, 1)
void rnn2_quad(const float* __restrict__ x, const float* __restrict__ hx,
               const float* __restrict__ w_ih0, const float* __restrict__ w_hh0,
               const float* __restrict__ b_ih0, const float* __restrict__ b_hh0,
               const float* __restrict__ w_ih1, const float* __restrict__ w_hh1,
               const float* __restrict__ b_ih1, const float* __restrict__ b_hh1,
               float* __restrict__ out)
{
    const int tid = threadIdx.x;
    const int c   = (blockIdx.x * 64 + tid) >> 2;   // chain id, 0..4095
    const int ja  = tid & 3;                        // slot-A unit; slot B = 4
    const float S = 2.8853900817779268f;

    // ---- weight pairs: w?p[k] = ( W[ja][k], W[4][k] ), pre-scaled by S ----
    v2f wi0p[ISZ], wh0p[HSZ], wi1p[HSZ], wh1p[HSZ];
    const v2f bias0p = (v2f){ S * (b_ih0[ja] + b_hh0[ja]), S * (b_ih0[4] + b_hh0[4]) };
    const v2f bias1p = (v2f){ S * (b_ih1[ja] + b_hh1[ja]), S * (b_ih1[4] + b_hh1[4]) };
#pragma unroll
    for (int i = 0; i < ISZ; i++)
        wi0p[i] = (v2f){ S * w_ih0[ja * ISZ + i], S * w_ih0[4 * ISZ + i] };
#pragma unroll
    for (int k = 0; k < HSZ; k++) {
        wh0p[k] = (v2f){ S * w_hh0[ja * HSZ + k], S * w_hh0[4 * HSZ + k] };
        wi1p[k] = (v2f){ S * w_ih1[ja * HSZ + k], S * w_ih1[4 * HSZ + k] };
        wh1p[k] = (v2f){ S * w_hh1[ja * HSZ + k], S * w_hh1[4 * HSZ + k] };
    }

    // ---- every lane holds the full state vectors (index 4 is lane-local) ----
    float h0b[HSZ], h1b[HSZ];
#pragma unroll
    for (int k = 0; k < HSZ; k++) {
        h0b[k] = hx[(size_t)c * HSZ + k];
        h1b[k] = hx[(size_t)BATCH * HSZ + (size_t)c * HSZ + k];
    }

    // ---- x modulo buffer: slot tt consumed, then refilled for next block ----
    const float* xp = x + (size_t)c * ISZ;
    float xbuf[KB][ISZ];
#pragma unroll
    for (int tt = 0; tt < KB; tt++)
#pragma unroll
        for (int i = 0; i < ISZ; i++)
            xbuf[tt][i] = xp[(size_t)tt * BATCH * ISZ + i];

    // lane's two output columns (lanes 1-3 dup-store unit 4: same addr+value)
    float* opA = out + (size_t)c * HSZ + ja;
    float* opB = out + (size_t)c * HSZ + 4;

    for (int blk = 0; blk < NBLK; blk++) {
        const int pf = (blk + 1 < NBLK) ? (blk + 1) * KB : blk * KB;
#pragma unroll
        for (int tt = 0; tt < KB; tt++) {
            const float xv0 = xbuf[tt][0], xv1 = xbuf[tt][1], xv2 = xbuf[tt][2];
            const float* xq = xp + (size_t)(pf + tt) * BATCH * ISZ;
            xbuf[tt][0] = xq[0]; xbuf[tt][1] = xq[1]; xbuf[tt][2] = xq[2];

            // layer 0, slots (ja, 4): accumulation order identical to R6
            v2f a = bias0p, cc = (v2f){0.0f, 0.0f};
            a  = vfma(xv0,    wi0p[0], a);
            cc = vfma(xv1,    wi0p[1], cc);
            a  = vfma(xv2,    wi0p[2], a);
            cc = vfma(h0b[0], wh0p[0], cc);
            a  = vfma(h0b[1], wh0p[1], a);
            cc = vfma(h0b[2], wh0p[2], cc);
            a  = vfma(h0b[3], wh0p[3], a);
            cc = vfma(h0b[4], wh0p[4], cc);
            a = a + cc;
            const float h0nA = tanh_fast(a.x);
            const float h0nB = tanh_fast(a.y);

            // broadcast units 0-3 within the quad (VALU DPP, independent);
            // unit 4 is lane-local (every lane computed it identically)
            h0b[0] = qbcast<0>(h0nA);
            h0b[1] = qbcast<1>(h0nA);
            h0b[2] = qbcast<2>(h0nA);
            h0b[3] = qbcast<3>(h0nA);
            h0b[4] = h0nB;

            // layer 1: reads NEW h0b, OLD h1b (Jacobi, matches reference)
            v2f d = bias1p, ee = (v2f){0.0f, 0.0f};
            d  = vfma(h0b[0], wi1p[0], d);
            ee = vfma(h0b[1], wi1p[1], ee);
            d  = vfma(h0b[2], wi1p[2], d);
            ee = vfma(h0b[3], wi1p[3], ee);
            d  = vfma(h0b[4], wi1p[4], d);
            ee = vfma(h1b[0], wh1p[0], ee);
            d  = vfma(h1b[1], wh1p[1], d);
            ee = vfma(h1b[2], wh1p[2], ee);
            d  = vfma(h1b[3], wh1p[3], d);
            ee = vfma(h1b[4], wh1p[4], ee);
            d = d + ee;
            const float h1nA = tanh_fast(d.x);
            const float h1nB = tanh_fast(d.y);

            // store own unit + unit 4 (dup lanes race benignly, same value)
            *opA = h1nA;
            *opB = h1nB;
            opA += (size_t)BATCH * HSZ;
            opB += (size_t)BATCH * HSZ;

            // h1 broadcast: next use is next step's layer 1 — ample slack
            h1b[0] = qbcast<0>(h1nA);
            h1b[1] = qbcast<1>(h1nA);
            h1b[2] = qbcast<2>(h1nA);
            h1b[3] = qbcast<3>(h1nA);
            h1b[4] = h1nB;
        }
    }

    // h_n = [h0_final, h1_final], appended after out[T,B,H].
    // h0b/h1b are identical across the quad's lanes -> 4x dup stores, benign.
    float* hn = out + (size_t)SEQ_T * BATCH * HSZ;
#pragma unroll
    for (int k = 0; k < HSZ; k++) {
        hn[(size_t)c * HSZ + k] = h0b[k];
        hn[(size_t)BATCH * HSZ + (size_t)c * HSZ + k] = h1b[k];
    }
}

extern "C" void kernel_launch(void* const* d_in, const int* in_sizes, int n_in,
                              void* d_out, int out_size, void* d_ws, size_t ws_size,
                              hipStream_t stream) {
    // 4096 chains x 4 lanes = 16384 threads; 64-thread blocks -> 256 blocks,
    // one wave per CU across all 256 CUs.
    rnn2_quad<<<(BATCH * 4) / 64, 64, 0, stream>>>(
        (const float*)d_in[0], (const float*)d_in[1],
        (const float*)d_in[2], (const float*)d_in[3],
        (const float*)d_in[4], (const float*)d_in[5],
        (const float*)d_in[6], (const float*)d_in[7],
        (const float*)d_in[8], (const float*)d_in[9],
        (float*)d_out);
}